// Round 3
// baseline (637.015 us; speedup 1.0000x reference)
//
#include <hip/hip_runtime.h>

#define NPIX 16384   // 128*128
#define BATCH 8

// ---------------- fully fused stage 1: x (B,32,256,256) -> o1 (B,64,128,128)
// Register-budgeted version: peak live ~110 VGPRs -> no scratch spill at the
// 128-VGPR / 2-blocks-per-CU operating point the 512-block grid provides.
__global__ void __launch_bounds__(256, 2)
stage1_fused_kernel(const float* __restrict__ x,
                    const float* __restrict__ w_red,   // (32,32)
                    const float* __restrict__ sg, const float* __restrict__ sb,
                    const float* __restrict__ sm, const float* __restrict__ sv,
                    const float* __restrict__ w_span,  // (9,32)
                    const float* __restrict__ w_init,  // (64,32)
                    const float* __restrict__ bg, const float* __restrict__ bb,
                    const float* __restrict__ bm, const float* __restrict__ bv,
                    const float* __restrict__ pr,
                    float* __restrict__ o1) {
    int blk = blockIdx.x;                 // 512 blocks: 8 b * 64 row-pairs
    int b = blk >> 6;
    int rg = blk & 63;
    int i = rg * 2 + (threadIdx.x >> 7);  // output row, wave-uniform
    int j = threadIdx.x & 127;            // output col
    const float* xb = x + ((size_t)b * 32) * 65536;

    // ---- pass A fused with reduce-matmul: acc32[c] = sum_m w_red[c][m]*pooled[m]
    // 4 channels per group: 8 loads in flight, live regs ~60.
    float acc32[32];
#pragma unroll
    for (int c = 0; c < 32; ++c) acc32[c] = 0.f;
    {
        const float* r0 = xb + (size_t)(2 * i) * 256 + 2 * j;
#pragma unroll
        for (int mg = 0; mg < 32; mg += 4) {
            float2 pa[4], pc[4];
#pragma unroll
            for (int mm = 0; mm < 4; ++mm) {
                const float* cp = r0 + (size_t)(mg + mm) * 65536;
                pa[mm] = *(const float2*)(cp);
                pc[mm] = *(const float2*)(cp + 256);
            }
            float p4[4];
#pragma unroll
            for (int mm = 0; mm < 4; ++mm)
                p4[mm] = 0.25f * ((pa[mm].x + pa[mm].y) + (pc[mm].x + pc[mm].y));
#pragma unroll
            for (int c = 0; c < 32; ++c) {
#pragma unroll
                for (int mm = 0; mm < 4; ++mm)
                    acc32[c] = fmaf(w_red[c * 32 + mg + mm], p4[mm], acc32[c]);
            }
        }
    }

    // ---- bn(1e-5) + relu + 32->9 span  -> k1[9]   (acc32 dies here)
    float k1[9];
#pragma unroll
    for (int r = 0; r < 9; ++r) k1[r] = 0.f;
#pragma unroll
    for (int c = 0; c < 32; ++c) {
        float sc = sg[c] * rsqrtf(sv[c] + 1e-5f);
        float tt = (acc32[c] - sm[c]) * sc + sb[c];
        tt = tt > 0.f ? tt : 0.f;
#pragma unroll
        for (int r = 0; r < 9; ++r) k1[r] = fmaf(w_span[r * 32 + c], tt, k1[r]);
    }

    // ---- pass B: involution (stride 2, pad 1, dil 1), 4 channels per group.
    // Live: k1[9] + p[32] + 48 window regs ~ 100.
    float p[32];
    int y0 = 2 * i - 1;                       // y0 >= -1; only i==0 underflows
    int coff = (j == 0) ? 0 : (2 * j - 2);    // clamped left float2
#pragma unroll
    for (int mg = 0; mg < 32; mg += 4) {
        float2 lo[4][3], hi[4][3];
#pragma unroll
        for (int mm = 0; mm < 4; ++mm) {
            const float* cb = xb + (size_t)(mg + mm) * 65536;
#pragma unroll
            for (int ky = 0; ky < 3; ++ky) {
                int y = y0 + ky;
                int yc = y < 0 ? 0 : y;
                const float* row = cb + (size_t)yc * 256;
                lo[mm][ky] = *(const float2*)(row + coff);   // cols [2j-2, 2j-1]
                hi[mm][ky] = *(const float2*)(row + 2 * j);  // cols [2j,   2j+1]
            }
        }
#pragma unroll
        for (int mm = 0; mm < 4; ++mm) {
            float acc = 0.f;
#pragma unroll
            for (int ky = 0; ky < 3; ++ky) {
                int y = y0 + ky;
                float t0 = (j == 0) ? 0.f : lo[mm][ky].y;
                float t1 = hi[mm][ky].x;
                float t2 = hi[mm][ky].y;
                if (y < 0) { t0 = 0.f; t1 = 0.f; t2 = 0.f; }
                acc = fmaf(k1[3 * ky + 0], t0, acc);
                acc = fmaf(k1[3 * ky + 1], t1, acc);
                acc = fmaf(k1[3 * ky + 2], t2, acc);
            }
            p[mg + mm] = acc;
        }
    }

    // ---- phase C: 1x1 conv 32->64 + bn(1e-3) + prelu, direct store
    float* ob = o1 + ((size_t)b * 64) * NPIX + (size_t)i * 128 + j;
#pragma unroll
    for (int c = 0; c < 64; ++c) {
        const float* wc = w_init + c * 32;
        float a0 = 0.f, a1 = 0.f, a2 = 0.f, a3 = 0.f;
#pragma unroll
        for (int m = 0; m < 32; m += 4) {
            float4 w4 = *(const float4*)(wc + m);       // uniform -> s_load_dwordx4
            a0 = fmaf(w4.x, p[m + 0], a0);
            a1 = fmaf(w4.y, p[m + 1], a1);
            a2 = fmaf(w4.z, p[m + 2], a2);
            a3 = fmaf(w4.w, p[m + 3], a3);
        }
        float sc = bg[c] * rsqrtf(bv[c] + 1e-3f);
        float v = ((a0 + a1) + (a2 + a3) - bm[c]) * sc + bb[c];
        v = v > 0.f ? v : pr[c] * v;
        ob[(size_t)c * NPIX] = v;
    }
}

// ---------------- kernel-gen for dilated stages, one stage per block
// o1 (B,64,128,128) -> k5 (5,B,9,128,128)
// inv[64]+kacc[9]+temps ~ 95 live VGPRs: cap 128, 4 waves/SIMD, no spill.
__global__ void __launch_bounds__(256, 4)
kgen5_kernel(const float* __restrict__ o1,
             const float* __restrict__ wred5,   // (5,64,64)
             const float* __restrict__ sg5, const float* __restrict__ sb5,
             const float* __restrict__ sm5, const float* __restrict__ sv5,
             const float* __restrict__ wspan5,  // (5,9,64)
             float* __restrict__ kout) {
    int blk = blockIdx.x;                                 // (P>>3)*40 + s*8 + (P&7); XCD = P%8
    int q = blk >> 3;
    int s = q % 5;
    int P = (q / 5) * 8 + (blk & 7);                      // [0,512)
    int gp = P * 256 + threadIdx.x;                       // global pixel id
    int b = gp >> 14;
    int pix = gp & (NPIX - 1);
    float inv[64];
    const float* base = o1 + ((size_t)b * 64) * NPIX + pix;
#pragma unroll
    for (int m = 0; m < 64; ++m) inv[m] = base[(size_t)m * NPIX];
    const float* wr = wred5 + s * 4096;
    const float* wsp = wspan5 + s * 576;
    const float* g = sg5 + s * 64;  const float* bt = sb5 + s * 64;
    const float* mn = sm5 + s * 64; const float* vr = sv5 + s * 64;
    float kacc[9];
#pragma unroll
    for (int r = 0; r < 9; ++r) kacc[r] = 0.f;
    for (int c = 0; c < 64; ++c) {
        float a0 = 0.f, a1 = 0.f, a2 = 0.f, a3 = 0.f;
#pragma unroll
        for (int m = 0; m < 64; m += 4) {
            a0 = fmaf(wr[c * 64 + m + 0], inv[m + 0], a0);
            a1 = fmaf(wr[c * 64 + m + 1], inv[m + 1], a1);
            a2 = fmaf(wr[c * 64 + m + 2], inv[m + 2], a2);
            a3 = fmaf(wr[c * 64 + m + 3], inv[m + 3], a3);
        }
        float acc = (a0 + a1) + (a2 + a3);
        float sc = g[c] * rsqrtf(vr[c] + 1e-5f);
        float tt = (acc - mn[c]) * sc + bt[c];
        tt = tt > 0.f ? tt : 0.f;
#pragma unroll
        for (int r = 0; r < 9; ++r) kacc[r] = fmaf(wsp[r * 64 + c], tt, kacc[r]);
    }
    float* ko = kout + ((size_t)(s * BATCH + b) * 9) * NPIX + pix;
#pragma unroll
    for (int r = 0; r < 9; ++r) ko[(size_t)r * NPIX] = kacc[r];
}

// ---------------- fused dilated involution: one stage's 4-pixel tile
template <int DIL>
__device__ __forceinline__ void invo_tap4(const float* __restrict__ xp,
                                          const float* __restrict__ kp,
                                          int i, int j0, float acc[4]) {
    constexpr int LOFF = (DIL < 4) ? 4 : DIL;
    float xw[3][12];
#pragma unroll
    for (int ky = 0; ky < 3; ++ky) {
        int y = i + DIL * (ky - 1);
        int yc = ((unsigned)y < 128u) ? y : i;            // safe row for OOB (zeroed later)
        const float* row = xp + (size_t)yc * 128;
        *(float4*)&xw[ky][0] = *(const float4*)(row + j0 - LOFF);  // guard offset covers underflow
        *(float4*)&xw[ky][4] = *(const float4*)(row + j0);
        *(float4*)&xw[ky][8] = *(const float4*)(row + j0 + LOFF);
    }
    float kv[36];
#pragma unroll
    for (int r = 0; r < 9; ++r) *(float4*)&kv[4 * r] = *(const float4*)(kp + (size_t)r * NPIX);
#pragma unroll
    for (int ky = 0; ky < 3; ++ky) {
        int y = i + DIL * (ky - 1);
        bool yok = (unsigned)y < 128u;
#pragma unroll
        for (int kx = 0; kx < 3; ++kx) {
#pragma unroll
            for (int pp = 0; pp < 4; ++pp) {
                int xx = j0 + pp + DIL * (kx - 1);
                bool ok = yok && ((kx == 1) || ((unsigned)xx < 128u));
                int widx = 4 + pp + ((DIL < 4) ? DIL : 4) * (kx - 1);
                float xv = ok ? xw[ky][widx] : 0.f;
                acc[pp] = fmaf(xv, kv[4 * (3 * ky + kx) + pp], acc[pp]);
            }
        }
    }
}

// xw[36]+kv[36]+acc+temps ~ 95 live VGPRs: cap 128, 4 waves/SIMD, no spill.
__global__ void __launch_bounds__(256, 4)
apply5_kernel(const float* __restrict__ o1, const float* __restrict__ kb, // (5,B,9,NPIX)
              const float* __restrict__ gd5, const float* __restrict__ bd5,
              const float* __restrict__ md5, const float* __restrict__ vd5,
              const float* __restrict__ ad5,
              const float* __restrict__ gf, const float* __restrict__ bf,
              const float* __restrict__ mf, const float* __restrict__ vf,
              const float* __restrict__ af,
              float* __restrict__ out) {
    int blk = blockIdx.x;                                 // 16 bpsHi * 64c * 8 bpsLo
    int low3 = blk & 7;
    int c = (blk >> 3) & 63;
    int bps = (blk >> 9) * 8 + low3;
    int b = bps >> 4, ps = bps & 15;
    int pix0 = ps * 1024 + threadIdx.x * 4;
    int i = pix0 >> 7, j0 = pix0 & 127;
    const float* xp = o1 + ((size_t)(b * 64 + c)) * NPIX;

#define STAGE(S, D)                                                            \
    {                                                                          \
        float acc[4] = {0.f, 0.f, 0.f, 0.f};                                   \
        const float* kp = kb + ((size_t)(S * BATCH + b) * 9) * NPIX + pix0;    \
        invo_tap4<D>(xp, kp, i, j0, acc);                                      \
        int sc = S * 64 + c;                                                   \
        float scd = gd5[sc] * rsqrtf(vd5[sc] + 1e-3f);                         \
        float scf = gf[sc] * rsqrtf(vf[sc] + 1e-3f);                           \
        float4 o; float* op = (float*)&o;                                      \
        _Pragma("unroll")                                                      \
        for (int pp = 0; pp < 4; ++pp) {                                       \
            float v = (acc[pp] - md5[sc]) * scd + bd5[sc];                     \
            v = v > 0.f ? v : ad5[sc] * v;                                     \
            v = (v - mf[sc]) * scf + bf[sc];                                   \
            v = v > 0.f ? v : af[sc] * v;                                      \
            op[pp] = v;                                                       \
        }                                                                      \
        *(float4*)(out + ((size_t)(b * 320 + sc)) * NPIX + pix0) = o;          \
    }
    STAGE(0, 1)
    STAGE(1, 2)
    STAGE(2, 4)
    STAGE(3, 8)
    STAGE(4, 16)
#undef STAGE
}

extern "C" void kernel_launch(void* const* d_in, const int* in_sizes, int n_in,
                              void* d_out, int out_size, void* d_ws, size_t ws_size,
                              hipStream_t stream) {
    const float* x       = (const float*)d_in[0];
    const float* w1_init = (const float*)d_in[1];
    const float* w1_red  = (const float*)d_in[2];
    const float* s1_g    = (const float*)d_in[3];
    const float* s1_b    = (const float*)d_in[4];
    const float* s1_m    = (const float*)d_in[5];
    const float* s1_v    = (const float*)d_in[6];
    const float* w1_span = (const float*)d_in[7];
    const float* bn1_g   = (const float*)d_in[8];
    const float* bn1_b   = (const float*)d_in[9];
    const float* bn1_m   = (const float*)d_in[10];
    const float* bn1_v   = (const float*)d_in[11];
    const float* pr1     = (const float*)d_in[12];
    const float* wd_red  = (const float*)d_in[13];  // (5,64,64)
    const float* sd_g    = (const float*)d_in[14];
    const float* sd_b    = (const float*)d_in[15];
    const float* sd_m    = (const float*)d_in[16];
    const float* sd_v    = (const float*)d_in[17];
    const float* wd_span = (const float*)d_in[18];  // (5,9,64)
    const float* bnd_g   = (const float*)d_in[19];
    const float* bnd_b   = (const float*)d_in[20];
    const float* bnd_m   = (const float*)d_in[21];
    const float* bnd_v   = (const float*)d_in[22];
    const float* prd     = (const float*)d_in[23];
    const float* bnf_g   = (const float*)d_in[24];
    const float* bnf_b   = (const float*)d_in[25];
    const float* bnf_m   = (const float*)d_in[26];
    const float* bnf_v   = (const float*)d_in[27];
    const float* prf     = (const float*)d_in[28];
    float* out = (float*)d_out;

    float* ws    = (float*)d_ws;
    float* o1buf = ws + 64;                    // +64 guard floats for j0-LOFF underflow
    float* k5buf = o1buf + 8388608;            // 8*64*16384

    const int TB = 256;

    hipLaunchKernelGGL(stage1_fused_kernel, dim3(512), dim3(TB), 0, stream,
                       x, w1_red, s1_g, s1_b, s1_m, s1_v, w1_span,
                       w1_init, bn1_g, bn1_b, bn1_m, bn1_v, pr1, o1buf);
    hipLaunchKernelGGL(kgen5_kernel, dim3(2560), dim3(TB), 0, stream,
                       o1buf, wd_red, sd_g, sd_b, sd_m, sd_v, wd_span, k5buf);
    hipLaunchKernelGGL(apply5_kernel, dim3(8192), dim3(TB), 0, stream,
                       o1buf, k5buf,
                       bnd_g, bnd_b, bnd_m, bnd_v, prd,
                       bnf_g, bnf_b, bnf_m, bnf_v, prf,
                       out);
}

// Round 5
// 528.303 us; speedup vs baseline: 1.2058x; 1.2058x over previous
//
#include <hip/hip_runtime.h>

#define NPIX 16384   // 128*128
#define BATCH 8

// ---------------- stage-1 kernel generation with fused 2x2 avg-pool
// x (B,32,256,256) -> k1 (B,9,128,128)            [round-0 proven version]
__global__ void kgen1_kernel(const float* __restrict__ x,
                             const float* __restrict__ w_red,   // (32,32)
                             const float* __restrict__ g,
                             const float* __restrict__ bta,
                             const float* __restrict__ mn,
                             const float* __restrict__ vr,
                             const float* __restrict__ w_span,  // (9,32)
                             float* __restrict__ kout) {
    int t = blockIdx.x * blockDim.x + threadIdx.x;        // B*NPIX threads
    int b = t >> 14;
    int pix = t & (NPIX - 1);
    int j = pix & 127, i = pix >> 7;
    float inv[32];
    const float* xb = x + ((size_t)b * 32) * 65536 + (size_t)(2 * i) * 256 + 2 * j;
#pragma unroll
    for (int m = 0; m < 32; ++m) {
        const float2* r0 = (const float2*)(xb + (size_t)m * 65536);
        const float2* r1 = (const float2*)(xb + (size_t)m * 65536 + 256);
        float2 a = r0[0], bb = r1[0];
        inv[m] = 0.25f * ((a.x + a.y) + (bb.x + bb.y));
    }
    float kacc[9];
#pragma unroll
    for (int r = 0; r < 9; ++r) kacc[r] = 0.f;
    for (int c = 0; c < 32; ++c) {
        float a0 = 0.f, a1 = 0.f, a2 = 0.f, a3 = 0.f;
#pragma unroll
        for (int m = 0; m < 32; m += 4) {
            a0 = fmaf(w_red[c * 32 + m + 0], inv[m + 0], a0);
            a1 = fmaf(w_red[c * 32 + m + 1], inv[m + 1], a1);
            a2 = fmaf(w_red[c * 32 + m + 2], inv[m + 2], a2);
            a3 = fmaf(w_red[c * 32 + m + 3], inv[m + 3], a3);
        }
        float acc = (a0 + a1) + (a2 + a3);
        float sc = g[c] * rsqrtf(vr[c] + 1e-5f);
        float tt = (acc - mn[c]) * sc + bta[c];
        tt = tt > 0.f ? tt : 0.f;
#pragma unroll
        for (int r = 0; r < 9; ++r) kacc[r] = fmaf(w_span[r * 32 + c], tt, kacc[r]);
    }
    float* ko = kout + ((size_t)b * 9) * NPIX + pix;
#pragma unroll
    for (int r = 0; r < 9; ++r) ko[(size_t)r * NPIX] = kacc[r];
}

// ---------------- fused involution-apply + 1x1 conv 32->64 + bn + prelu
// Channel-split 4-ways: thread = (pixel, quarter).  Wave q of a block does
// involution for input channels [8q,8q+8) of 64 pixels, shares p via LDS,
// then computes output channels [16q,16q+16).  8 blocks/CU, 32 waves/CU.
__global__ void applyconv_kernel(const float* __restrict__ x,
                                 const float* __restrict__ kb,   // (B,9,NPIX)
                                 const float* __restrict__ w,    // (64,32) w1_init
                                 const float* __restrict__ g, const float* __restrict__ bt,
                                 const float* __restrict__ mn, const float* __restrict__ vr,
                                 const float* __restrict__ pr,
                                 float* __restrict__ o1) {
    __shared__ float lds_p[64][33];        // pad 33: phase-C read is 2-way (free)
    int lane = threadIdx.x & 63;
    int q = threadIdx.x >> 6;              // wave id 0..3
    int gp = blockIdx.x * 64 + lane;       // global pixel id (64 px per block)
    int b = gp >> 14;
    int pix = gp & (NPIX - 1);
    int i = pix >> 7, j = pix & 127;       // i, b wave-uniform (64-aligned chunks)
    const float* xb = x + ((size_t)b * 32) * 65536;

    // per-pixel dynamic kernel
    float k1[9];
    const float* kp = kb + ((size_t)b * 9) * NPIX + pix;
#pragma unroll
    for (int r = 0; r < 9; ++r) k1[r] = kp[(size_t)r * NPIX];

    // involution (stride 2, pad 1, dil 1) for this wave's 8 input channels
    int y0 = 2 * i - 1;                    // >= -1; only i==0 underflows
    int coff = (j == 0) ? 0 : (2 * j - 2); // clamped left float2
#pragma unroll
    for (int mg = 0; mg < 8; mg += 2) {
        float2 lo[2][3], hi[2][3];
#pragma unroll
        for (int mm = 0; mm < 2; ++mm) {
            const float* cb = xb + (size_t)(8 * q + mg + mm) * 65536;
#pragma unroll
            for (int ky = 0; ky < 3; ++ky) {
                int y = y0 + ky;
                int yc = y < 0 ? 0 : y;
                const float* row = cb + (size_t)yc * 256;
                lo[mm][ky] = *(const float2*)(row + coff);   // cols [2j-2, 2j-1]
                hi[mm][ky] = *(const float2*)(row + 2 * j);  // cols [2j,   2j+1]
            }
        }
#pragma unroll
        for (int mm = 0; mm < 2; ++mm) {
            float acc = 0.f;
#pragma unroll
            for (int ky = 0; ky < 3; ++ky) {
                int y = y0 + ky;
                float t0 = (j == 0) ? 0.f : lo[mm][ky].y;
                float t1 = hi[mm][ky].x;
                float t2 = hi[mm][ky].y;
                if (y < 0) { t0 = 0.f; t1 = 0.f; t2 = 0.f; }
                acc = fmaf(k1[3 * ky + 0], t0, acc);
                acc = fmaf(k1[3 * ky + 1], t1, acc);
                acc = fmaf(k1[3 * ky + 2], t2, acc);
            }
            lds_p[lane][8 * q + mg + mm] = acc;
        }
    }
    __syncthreads();

    // 1x1 conv 32->64: this wave handles out channels [16q, 16q+16) for its pixel
    float pv[32];
#pragma unroll
    for (int m = 0; m < 32; ++m) pv[m] = lds_p[lane][m];
    float* ob = o1 + ((size_t)b * 64) * NPIX + pix;
#pragma unroll
    for (int cc = 0; cc < 16; ++cc) {
        int c = 16 * q + cc;               // wave-uniform -> scalar weight loads
        const float* wc = w + c * 32;
        float a0 = 0.f, a1 = 0.f, a2 = 0.f, a3 = 0.f;
#pragma unroll
        for (int m = 0; m < 32; m += 4) {
            float4 w4 = *(const float4*)(wc + m);
            a0 = fmaf(w4.x, pv[m + 0], a0);
            a1 = fmaf(w4.y, pv[m + 1], a1);
            a2 = fmaf(w4.z, pv[m + 2], a2);
            a3 = fmaf(w4.w, pv[m + 3], a3);
        }
        float sc = g[c] * rsqrtf(vr[c] + 1e-3f);
        float v = ((a0 + a1) + (a2 + a3) - mn[c]) * sc + bt[c];
        v = v > 0.f ? v : pr[c] * v;
        ob[(size_t)c * NPIX] = v;
    }
}

// ---------------- kernel-gen for dilated stages, one stage per block
// o1 (B,64,128,128) -> k5 (5,B,9,128,128)         [round-1 config: no bounds]
__global__ void kgen5_kernel(const float* __restrict__ o1,
                             const float* __restrict__ wred5,   // (5,64,64)
                             const float* __restrict__ sg5, const float* __restrict__ sb5,
                             const float* __restrict__ sm5, const float* __restrict__ sv5,
                             const float* __restrict__ wspan5,  // (5,9,64)
                             float* __restrict__ kout) {
    int blk = blockIdx.x;                                 // (P>>3)*40 + s*8 + (P&7); XCD = P%8
    int q = blk >> 3;
    int s = q % 5;
    int P = (q / 5) * 8 + (blk & 7);                      // [0,512)
    int gp = P * 256 + threadIdx.x;                       // global pixel id
    int b = gp >> 14;
    int pix = gp & (NPIX - 1);
    float inv[64];
    const float* base = o1 + ((size_t)b * 64) * NPIX + pix;
#pragma unroll
    for (int m = 0; m < 64; ++m) inv[m] = base[(size_t)m * NPIX];
    const float* wr = wred5 + s * 4096;
    const float* wsp = wspan5 + s * 576;
    const float* g = sg5 + s * 64;  const float* bt = sb5 + s * 64;
    const float* mn = sm5 + s * 64; const float* vr = sv5 + s * 64;
    float kacc[9];
#pragma unroll
    for (int r = 0; r < 9; ++r) kacc[r] = 0.f;
    for (int c = 0; c < 64; ++c) {
        float a0 = 0.f, a1 = 0.f, a2 = 0.f, a3 = 0.f;
#pragma unroll
        for (int m = 0; m < 64; m += 4) {
            a0 = fmaf(wr[c * 64 + m + 0], inv[m + 0], a0);
            a1 = fmaf(wr[c * 64 + m + 1], inv[m + 1], a1);
            a2 = fmaf(wr[c * 64 + m + 2], inv[m + 2], a2);
            a3 = fmaf(wr[c * 64 + m + 3], inv[m + 3], a3);
        }
        float acc = (a0 + a1) + (a2 + a3);
        float sc = g[c] * rsqrtf(vr[c] + 1e-5f);
        float tt = (acc - mn[c]) * sc + bt[c];
        tt = tt > 0.f ? tt : 0.f;
#pragma unroll
        for (int r = 0; r < 9; ++r) kacc[r] = fmaf(wsp[r * 64 + c], tt, kacc[r]);
    }
    float* ko = kout + ((size_t)(s * BATCH + b) * 9) * NPIX + pix;
#pragma unroll
    for (int r = 0; r < 9; ++r) ko[(size_t)r * NPIX] = kacc[r];
}

// ---------------- fused dilated involution: one stage's 4-pixel tile
template <int DIL>
__device__ __forceinline__ void invo_tap4(const float* __restrict__ xp,
                                          const float* __restrict__ kp,
                                          int i, int j0, float acc[4]) {
    constexpr int LOFF = (DIL < 4) ? 4 : DIL;
    float xw[3][12];
#pragma unroll
    for (int ky = 0; ky < 3; ++ky) {
        int y = i + DIL * (ky - 1);
        int yc = ((unsigned)y < 128u) ? y : i;            // safe row for OOB (zeroed later)
        const float* row = xp + (size_t)yc * 128;
        *(float4*)&xw[ky][0] = *(const float4*)(row + j0 - LOFF);  // guard offset covers underflow
        *(float4*)&xw[ky][4] = *(const float4*)(row + j0);
        *(float4*)&xw[ky][8] = *(const float4*)(row + j0 + LOFF);
    }
    float kv[36];
#pragma unroll
    for (int r = 0; r < 9; ++r) *(float4*)&kv[4 * r] = *(const float4*)(kp + (size_t)r * NPIX);
#pragma unroll
    for (int ky = 0; ky < 3; ++ky) {
        int y = i + DIL * (ky - 1);
        bool yok = (unsigned)y < 128u;
#pragma unroll
        for (int kx = 0; kx < 3; ++kx) {
#pragma unroll
            for (int pp = 0; pp < 4; ++pp) {
                int xx = j0 + pp + DIL * (kx - 1);
                bool ok = yok && ((kx == 1) || ((unsigned)xx < 128u));
                int widx = 4 + pp + ((DIL < 4) ? DIL : 4) * (kx - 1);
                float xv = ok ? xw[ky][widx] : 0.f;
                acc[pp] = fmaf(xv, kv[4 * (3 * ky + kx) + pp], acc[pp]);
            }
        }
    }
}

__global__ void apply5_kernel(const float* __restrict__ o1, const float* __restrict__ kb, // (5,B,9,NPIX)
                              const float* __restrict__ gd5, const float* __restrict__ bd5,
                              const float* __restrict__ md5, const float* __restrict__ vd5,
                              const float* __restrict__ ad5,
                              const float* __restrict__ gf, const float* __restrict__ bf,
                              const float* __restrict__ mf, const float* __restrict__ vf,
                              const float* __restrict__ af,
                              float* __restrict__ out) {
    int blk = blockIdx.x;                                 // 16 bpsHi * 64c * 8 bpsLo
    int low3 = blk & 7;
    int c = (blk >> 3) & 63;
    int bps = (blk >> 9) * 8 + low3;
    int b = bps >> 4, ps = bps & 15;
    int pix0 = ps * 1024 + threadIdx.x * 4;
    int i = pix0 >> 7, j0 = pix0 & 127;
    const float* xp = o1 + ((size_t)(b * 64 + c)) * NPIX;

#define STAGE(S, D)                                                            \
    {                                                                          \
        float acc[4] = {0.f, 0.f, 0.f, 0.f};                                   \
        const float* kp = kb + ((size_t)(S * BATCH + b) * 9) * NPIX + pix0;    \
        invo_tap4<D>(xp, kp, i, j0, acc);                                      \
        int sc = S * 64 + c;                                                   \
        float scd = gd5[sc] * rsqrtf(vd5[sc] + 1e-3f);                         \
        float scf = gf[sc] * rsqrtf(vf[sc] + 1e-3f);                           \
        float4 o; float* op = (float*)&o;                                      \
        _Pragma("unroll")                                                      \
        for (int pp = 0; pp < 4; ++pp) {                                       \
            float v = (acc[pp] - md5[sc]) * scd + bd5[sc];                     \
            v = v > 0.f ? v : ad5[sc] * v;                                     \
            v = (v - mf[sc]) * scf + bf[sc];                                   \
            v = v > 0.f ? v : af[sc] * v;                                      \
            op[pp] = v;                                                       \
        }                                                                      \
        *(float4*)(out + ((size_t)(b * 320 + sc)) * NPIX + pix0) = o;          \
    }
    STAGE(0, 1)
    STAGE(1, 2)
    STAGE(2, 4)
    STAGE(3, 8)
    STAGE(4, 16)
#undef STAGE
}

extern "C" void kernel_launch(void* const* d_in, const int* in_sizes, int n_in,
                              void* d_out, int out_size, void* d_ws, size_t ws_size,
                              hipStream_t stream) {
    const float* x       = (const float*)d_in[0];
    const float* w1_init = (const float*)d_in[1];
    const float* w1_red  = (const float*)d_in[2];
    const float* s1_g    = (const float*)d_in[3];
    const float* s1_b    = (const float*)d_in[4];
    const float* s1_m    = (const float*)d_in[5];
    const float* s1_v    = (const float*)d_in[6];
    const float* w1_span = (const float*)d_in[7];
    const float* bn1_g   = (const float*)d_in[8];
    const float* bn1_b   = (const float*)d_in[9];
    const float* bn1_m   = (const float*)d_in[10];
    const float* bn1_v   = (const float*)d_in[11];
    const float* pr1     = (const float*)d_in[12];
    const float* wd_red  = (const float*)d_in[13];  // (5,64,64)
    const float* sd_g    = (const float*)d_in[14];
    const float* sd_b    = (const float*)d_in[15];
    const float* sd_m    = (const float*)d_in[16];
    const float* sd_v    = (const float*)d_in[17];
    const float* wd_span = (const float*)d_in[18];  // (5,9,64)
    const float* bnd_g   = (const float*)d_in[19];
    const float* bnd_b   = (const float*)d_in[20];
    const float* bnd_m   = (const float*)d_in[21];
    const float* bnd_v   = (const float*)d_in[22];
    const float* prd     = (const float*)d_in[23];
    const float* bnf_g   = (const float*)d_in[24];
    const float* bnf_b   = (const float*)d_in[25];
    const float* bnf_m   = (const float*)d_in[26];
    const float* bnf_v   = (const float*)d_in[27];
    const float* prf     = (const float*)d_in[28];
    float* out = (float*)d_out;

    float* ws    = (float*)d_ws;
    float* o1buf = ws + 64;                    // +64 guard floats for j0-LOFF underflow
    float* k5buf = o1buf + 8388608;            // 8*64*16384
    float* k1buf = k5buf + 5898240;            // 5*8*9*16384

    const int TB = 256;

    hipLaunchKernelGGL(kgen1_kernel, dim3(BATCH * NPIX / TB), dim3(TB), 0, stream,
                       x, w1_red, s1_g, s1_b, s1_m, s1_v, w1_span, k1buf);
    hipLaunchKernelGGL(applyconv_kernel, dim3(2048), dim3(TB), 0, stream,
                       x, k1buf, w1_init, bn1_g, bn1_b, bn1_m, bn1_v, pr1, o1buf);
    hipLaunchKernelGGL(kgen5_kernel, dim3(2560), dim3(TB), 0, stream,
                       o1buf, wd_red, sd_g, sd_b, sd_m, sd_v, wd_span, k5buf);
    hipLaunchKernelGGL(apply5_kernel, dim3(8192), dim3(TB), 0, stream,
                       o1buf, k5buf,
                       bnd_g, bnd_b, bnd_m, bnd_v, prd,
                       bnf_g, bnf_b, bnf_m, bnf_v, prf,
                       out);
}